// Round 3
// baseline (1169.500 us; speedup 1.0000x reference)
//
#include <hip/hip_runtime.h>
#include <hip/hip_cooperative_groups.h>
#include <math.h>

namespace cg = cooperative_groups;

// Problem constants
#define HH   1024
#define SS   5
#define LL   4
#define INW  42
#define CC   500

__device__ __forceinline__ float sigf(float v) { return 1.0f / (1.0f + expf(-v)); }

__device__ __forceinline__ float wave_sum(float v) {
#pragma unroll
    for (int m = 32; m >= 1; m >>= 1) v += __shfl_xor(v, m, 64);
    return v;
}

// Dead code proven by reference structure (verified absmax=0.0 in round 2):
//  - h0/c0 stay zero for every layer  -> W_hh never contributes, f-gate dead
//  - softmax over length-1 axis == 1  -> ctx == fused; att_*/score_* dead
//
// One cooperative kernel, 640 blocks x 256 threads (2560 waves, co-resident).
// Each wave owns (s, j0..j0+1): 6 live gate rows per layer, contiguous pairs.
// Phases separated by grid.sync(): P0 prep+layer0, P1-P3 recurrent layers,
// P4 fuse, P5 fc.
__global__ __launch_bounds__(256, 3) void fused_all(
    const float* __restrict__ x,      // (1,133,2)
    const float* __restrict__ W_ih0,  // (S,4H,INW)
    const float* __restrict__ W_ihr,  // (S,L-1,4H,H)
    const float* __restrict__ b_ih,   // (S,L,4H)
    const float* __restrict__ b_hh,   // (S,L,4H)
    const float* __restrict__ fuse_w, // (H, S*H)
    const float* __restrict__ fuse_b, // (H)
    const float* __restrict__ fc_w,   // (C, H)
    const float* __restrict__ fc_b,   // (C)
    float* __restrict__ out,          // (C)
    float* __restrict__ ws)
{
    cg::grid_group grid = cg::this_grid();
    const int wid  = (blockIdx.x << 2) + (threadIdx.x >> 6);  // 0..2559
    const int lane = threadIdx.x & 63;
    const int s    = wid >> 9;          // 0..4
    const int j0   = (wid & 511) << 1;  // 0,2,...,1022

    float* hA    = ws;            // 5120
    float* hB    = ws + 5120;     // 5120
    float* fused = ws + 10240;    // 1024

    // ---------------- Phase 0: prep (in-register) + layer 0 ----------------
    {
        // prep stats (tiny, fully L1-cached; every lane computes them)
        const float sbx = x[0],   sby = x[1];
        const float slx = x[200], sly = x[201];
        const float srx = x[242], sry = x[243];
        float lminx = 1e30f, lmaxx = -1e30f, lminy = 1e30f, lmaxy = -1e30f;
        float rminx = 1e30f, rmaxx = -1e30f, rminy = 1e30f, rmaxy = -1e30f;
        for (int i = 0; i < 21; ++i) {
            float lx = x[(91 + i) * 2 + 0], ly = x[(91 + i) * 2 + 1];
            float rx = x[(112 + i) * 2 + 0], ry = x[(112 + i) * 2 + 1];
            lminx = fminf(lminx, lx); lmaxx = fmaxf(lmaxx, lx);
            lminy = fminf(lminy, ly); lmaxy = fmaxf(lmaxy, ly);
            rminx = fminf(rminx, rx); rmaxx = fmaxf(rmaxx, rx);
            rminy = fminf(rminy, ry); rmaxy = fmaxf(rmaxy, ry);
        }
        float w_l = lmaxx - lminx, h_l = lmaxy - lminy;
        float w_r = rmaxx - rminx, h_r = rmaxy - rminy;
        float w_b = x[10] - x[12];
        float h_b = 4.0f * w_b;
        bool cl = (w_l != 0.0f) && (h_l != 0.0f);
        float dlx = cl ? w_l : 1.0f, dly = cl ? h_l : 1.0f;
        bool cr = (w_r != 0.0f) && (h_r != 0.0f);
        float drx = cr ? w_r : 1.0f, dry = cr ? h_r : 1.0f;
        bool cb = (w_b != 0.0f) && (h_b != 0.0f);
        float wb = cb ? w_b : 1.0f, hb = cb ? h_b : 1.0f;

        // xs[s][lane] for lane<42
        float xv = 0.0f;
        if (lane < INW) {
            int idx = s * INW + lane;        // 0..209
            int p = idx >> 1, coord = idx & 1;
            int grp = p / 21, i = p % 21;
            float lc = x[(91 + i) * 2 + coord];
            float rc = x[(112 + i) * 2 + coord];
            switch (grp) {
                case 0: xv = (lc - (coord ? sly : slx)) / (coord ? dly : dlx); break;
                case 1: xv = (rc - (coord ? sry : srx)) / (coord ? dry : drx); break;
                case 2: xv = (lc - (coord ? sby : sbx)) / (coord ? 1.0f : wb); break;
                case 3: xv = (rc - (coord ? sby : sbx)) / (coord ? hb : 1.0f); break;
                default: xv = (lc - rc) / (coord ? hb : wb); break;
            }
        }

        const float* Ws = W_ih0 + (size_t)s * 4096 * INW;
        float a0 = 0, a1 = 0, a2 = 0, a3 = 0, a4 = 0, a5 = 0;
        if (lane < INW) {
            a0 = Ws[(size_t)(j0) * INW + lane] * xv;
            a1 = Ws[(size_t)(j0 + 1) * INW + lane] * xv;
            a2 = Ws[(size_t)(2048 + j0) * INW + lane] * xv;
            a3 = Ws[(size_t)(2048 + j0 + 1) * INW + lane] * xv;
            a4 = Ws[(size_t)(3072 + j0) * INW + lane] * xv;
            a5 = Ws[(size_t)(3072 + j0 + 1) * INW + lane] * xv;
        }
        a0 = wave_sum(a0); a1 = wave_sum(a1); a2 = wave_sum(a2);
        a3 = wave_sum(a3); a4 = wave_sum(a4); a5 = wave_sum(a5);

        if (lane == 0) {
            const float* bi = b_ih + (size_t)(s * LL + 0) * 4096;
            const float* bh = b_hh + (size_t)(s * LL + 0) * 4096;
            float gi0 = a0 + bi[j0] + bh[j0];
            float gi1 = a1 + bi[j0 + 1] + bh[j0 + 1];
            float gg0 = a2 + bi[2048 + j0] + bh[2048 + j0];
            float gg1 = a3 + bi[2048 + j0 + 1] + bh[2048 + j0 + 1];
            float go0 = a4 + bi[3072 + j0] + bh[3072 + j0];
            float go1 = a5 + bi[3072 + j0 + 1] + bh[3072 + j0 + 1];
            hA[s * HH + j0]     = sigf(go0) * tanhf(sigf(gi0) * tanhf(gg0));
            hA[s * HH + j0 + 1] = sigf(go1) * tanhf(sigf(gi1) * tanhf(gg1));
        }
    }
    __threadfence();
    grid.sync();

    // ---------------- Phases 1..3: recurrent layers ----------------
#pragma unroll
    for (int layer = 1; layer < LL; ++layer) {
        const float* hin  = (layer & 1) ? hA : hB;   // P1: A->B, P2: B->A, P3: A->B
        float*       hout = (layer & 1) ? hB : hA;

        const float* Ws = W_ihr + (size_t)(s * (LL - 1) + (layer - 1)) * 4096 * HH;
        const float4* r0 = (const float4*)(Ws + (size_t)(j0) * HH);
        const float4* r1 = (const float4*)(Ws + (size_t)(j0 + 1) * HH);
        const float4* r2 = (const float4*)(Ws + (size_t)(2048 + j0) * HH);
        const float4* r3 = (const float4*)(Ws + (size_t)(2048 + j0 + 1) * HH);
        const float4* r4 = (const float4*)(Ws + (size_t)(3072 + j0) * HH);
        const float4* r5 = (const float4*)(Ws + (size_t)(3072 + j0 + 1) * HH);
        const float4* hv = (const float4*)(hin + s * HH);

        float a0 = 0, a1 = 0, a2 = 0, a3 = 0, a4 = 0, a5 = 0;
#pragma unroll
        for (int k = 0; k < 4; ++k) {
            int idx = (k << 6) + lane;
            float4 h4 = hv[idx];
            float4 w;
            w = r0[idx]; a0 += w.x * h4.x + w.y * h4.y + w.z * h4.z + w.w * h4.w;
            w = r1[idx]; a1 += w.x * h4.x + w.y * h4.y + w.z * h4.z + w.w * h4.w;
            w = r2[idx]; a2 += w.x * h4.x + w.y * h4.y + w.z * h4.z + w.w * h4.w;
            w = r3[idx]; a3 += w.x * h4.x + w.y * h4.y + w.z * h4.z + w.w * h4.w;
            w = r4[idx]; a4 += w.x * h4.x + w.y * h4.y + w.z * h4.z + w.w * h4.w;
            w = r5[idx]; a5 += w.x * h4.x + w.y * h4.y + w.z * h4.z + w.w * h4.w;
        }
        a0 = wave_sum(a0); a1 = wave_sum(a1); a2 = wave_sum(a2);
        a3 = wave_sum(a3); a4 = wave_sum(a4); a5 = wave_sum(a5);

        if (lane == 0) {
            const float* bi = b_ih + (size_t)(s * LL + layer) * 4096;
            const float* bh = b_hh + (size_t)(s * LL + layer) * 4096;
            float gi0 = a0 + bi[j0] + bh[j0];
            float gi1 = a1 + bi[j0 + 1] + bh[j0 + 1];
            float gg0 = a2 + bi[2048 + j0] + bh[2048 + j0];
            float gg1 = a3 + bi[2048 + j0 + 1] + bh[2048 + j0 + 1];
            float go0 = a4 + bi[3072 + j0] + bh[3072 + j0];
            float go1 = a5 + bi[3072 + j0 + 1] + bh[3072 + j0 + 1];
            hout[s * HH + j0]     = sigf(go0) * tanhf(sigf(gi0) * tanhf(gg0));
            hout[s * HH + j0 + 1] = sigf(go1) * tanhf(sigf(gi1) * tanhf(gg1));
        }
        __threadfence();
        grid.sync();
    }

    // ---------------- Phase 4: fuse (final h is in hB) ----------------
    if (wid < HH) {
        const float4* row = (const float4*)(fuse_w + (size_t)wid * (SS * HH));
        const float4* hv  = (const float4*)hB;
        float a = 0.0f;
#pragma unroll
        for (int k = 0; k < 20; ++k) {
            int idx = (k << 6) + lane;
            float4 w = row[idx];
            float4 h = hv[idx];
            a += w.x * h.x + w.y * h.y + w.z * h.z + w.w * h.w;
        }
        a = wave_sum(a);
        if (lane == 0) fused[wid] = a + fuse_b[wid];
    }
    __threadfence();
    grid.sync();

    // ---------------- Phase 5: fc ----------------
    if (wid < CC) {
        const float4* row = (const float4*)(fc_w + (size_t)wid * HH);
        const float4* hv  = (const float4*)fused;
        float a = 0.0f;
#pragma unroll
        for (int k = 0; k < 4; ++k) {
            int idx = (k << 6) + lane;
            float4 w = row[idx];
            float4 h = hv[idx];
            a += w.x * h.x + w.y * h.y + w.z * h.z + w.w * h.w;
        }
        a = wave_sum(a);
        if (lane == 0) out[wid] = a + fc_b[wid];
    }
}

extern "C" void kernel_launch(void* const* d_in, const int* in_sizes, int n_in,
                              void* d_out, int out_size, void* d_ws, size_t ws_size,
                              hipStream_t stream) {
    const float* x      = (const float*)d_in[0];
    const float* W_ih0  = (const float*)d_in[1];
    const float* W_ihr  = (const float*)d_in[2];
    // d_in[3] = W_hh : multiplied by h0 == 0, never read
    const float* b_ih   = (const float*)d_in[4];
    const float* b_hh   = (const float*)d_in[5];
    const float* fuse_w = (const float*)d_in[6];
    const float* fuse_b = (const float*)d_in[7];
    // d_in[8..11] = att_w, att_b, score_w, score_b : softmax over len-1 axis => no-op
    const float* fc_w   = (const float*)d_in[12];
    const float* fc_b   = (const float*)d_in[13];
    float* out = (float*)d_out;
    float* wsf = (float*)d_ws;

    void* args[] = { (void*)&x, (void*)&W_ih0, (void*)&W_ihr, (void*)&b_ih,
                     (void*)&b_hh, (void*)&fuse_w, (void*)&fuse_b, (void*)&fc_w,
                     (void*)&fc_b, (void*)&out, (void*)&wsf };
    hipLaunchCooperativeKernel((const void*)fused_all, dim3(640), dim3(256),
                               args, 0, stream);
}

// Round 4
// 542.861 us; speedup vs baseline: 2.1543x; 2.1543x over previous
//
#include <hip/hip_runtime.h>
#include <math.h>

// Problem constants
#define HH   1024
#define SS   5
#define LL   4
#define INW  42
#define CC   500

// ws layout (float offsets)
#define WS_HA     0      // 5120 floats
#define WS_HB     5632   // 5120 floats
#define WS_FUSED  11264  // 1024 floats

__device__ __forceinline__ float sigf(float v) { return 1.0f / (1.0f + expf(-v)); }

__device__ __forceinline__ float wave_sum(float v) {
#pragma unroll
    for (int m = 32; m >= 1; m >>= 1) v += __shfl_xor(v, m, 64);
    return v;
}

__device__ __forceinline__ float dot4(float4 w, float4 h) {
    return w.x * h.x + w.y * h.y + w.z * h.z + w.w * h.w;
}

// Dead code proven by reference structure (absmax=0.0 in rounds 2 & 3):
//  - h0/c0 stay zero for every layer  -> W_hh never contributes, f-gate dead
//  - softmax over length-1 axis == 1  -> ctx == fused; att_*/score_* dead
// Round 3 lesson: cooperative grid.sync costs ~135us/sync here; plain kernel
// launch boundaries (~2-4us in a captured graph) are the cheapest barrier.

// ---------------------------------------------------------------------------
// 1) prep (in-register, ~1KB of x, L1-resident) + layer 0.
//    One wave per (s, j). f-gate rows and W_hh@0 skipped (h0==c0==0).
// ---------------------------------------------------------------------------
__global__ __launch_bounds__(256) void layer0_prep_kernel(
    const float* __restrict__ x,     // (1,133,2)
    const float* __restrict__ W,     // (S, 4H, INW)
    const float* __restrict__ b_ih,  // (S, L, 4H)
    const float* __restrict__ b_hh,  // (S, L, 4H)
    float* __restrict__ hout)        // (S, H)
{
    int wid = (blockIdx.x << 2) + (threadIdx.x >> 6);
    int lane = threadIdx.x & 63;
    int s = wid >> 10, j = wid & 1023;

    // --- prep stats (every thread; broadcast loads hit L1) ---
    const float sbx = x[0],   sby = x[1];
    const float slx = x[200], sly = x[201];
    const float srx = x[242], sry = x[243];
    float lminx = 1e30f, lmaxx = -1e30f, lminy = 1e30f, lmaxy = -1e30f;
    float rminx = 1e30f, rmaxx = -1e30f, rminy = 1e30f, rmaxy = -1e30f;
    for (int i = 0; i < 21; ++i) {
        float lx = x[(91 + i) * 2 + 0], ly = x[(91 + i) * 2 + 1];
        float rx = x[(112 + i) * 2 + 0], ry = x[(112 + i) * 2 + 1];
        lminx = fminf(lminx, lx); lmaxx = fmaxf(lmaxx, lx);
        lminy = fminf(lminy, ly); lmaxy = fmaxf(lmaxy, ly);
        rminx = fminf(rminx, rx); rmaxx = fmaxf(rmaxx, rx);
        rminy = fminf(rminy, ry); rmaxy = fmaxf(rmaxy, ry);
    }
    float w_l = lmaxx - lminx, h_l = lmaxy - lminy;
    float w_r = rmaxx - rminx, h_r = rmaxy - rminy;
    float w_b = x[10] - x[12];
    float h_b = 4.0f * w_b;
    bool cl = (w_l != 0.0f) && (h_l != 0.0f);
    float dlx = cl ? w_l : 1.0f, dly = cl ? h_l : 1.0f;
    bool cr = (w_r != 0.0f) && (h_r != 0.0f);
    float drx = cr ? w_r : 1.0f, dry = cr ? h_r : 1.0f;
    bool cb = (w_b != 0.0f) && (h_b != 0.0f);
    float wb = cb ? w_b : 1.0f, hb = cb ? h_b : 1.0f;

    // xs[s][lane] for lane<42, in-register
    float xv = 0.0f;
    if (lane < INW) {
        int idx = s * INW + lane;        // 0..209
        int p = idx >> 1, coord = idx & 1;
        int grp = p / 21, i = p % 21;
        float lc = x[(91 + i) * 2 + coord];
        float rc = x[(112 + i) * 2 + coord];
        switch (grp) {
            case 0: xv = (lc - (coord ? sly : slx)) / (coord ? dly : dlx); break;
            case 1: xv = (rc - (coord ? sry : srx)) / (coord ? dry : drx); break;
            case 2: xv = (lc - (coord ? sby : sbx)) / (coord ? 1.0f : wb); break;
            case 3: xv = (rc - (coord ? sby : sbx)) / (coord ? hb : 1.0f); break;
            default: xv = (lc - rc) / (coord ? hb : wb); break;
        }
    }

    const float* Ws = W + (size_t)s * 4096 * INW;
    float ai = 0.0f, ag = 0.0f, ao = 0.0f;
    if (lane < INW) {
        ai = Ws[(size_t)(j) * INW + lane] * xv;
        ag = Ws[(size_t)(2048 + j) * INW + lane] * xv;
        ao = Ws[(size_t)(3072 + j) * INW + lane] * xv;
    }
    ai = wave_sum(ai); ag = wave_sum(ag); ao = wave_sum(ao);

    if (lane == 0) {
        const float* bi = b_ih + (size_t)(s * LL + 0) * 4096;
        const float* bh = b_hh + (size_t)(s * LL + 0) * 4096;
        float gi = ai + bi[j] + bh[j];
        float gg = ag + bi[2048 + j] + bh[2048 + j];
        float go = ao + bi[3072 + j] + bh[3072 + j];
        float c = sigf(gi) * tanhf(gg);
        hout[s * HH + j] = sigf(go) * tanhf(c);
    }
}

// ---------------------------------------------------------------------------
// 2) Layers 1..3: gates = W_ihr[s,layer-1] @ h[s] + b ; same activation.
//    One wave per (s, j). All 16 float4 loads issued before any FMA (MLP).
// ---------------------------------------------------------------------------
__global__ __launch_bounds__(256) void layer_kernel(
    const float* __restrict__ W,     // (S, L-1, 4H, H)
    const float* __restrict__ b_ih,
    const float* __restrict__ b_hh,
    int layer,                       // 1..3
    const float* __restrict__ hin,   // (S, H)
    float* __restrict__ hout)        // (S, H)
{
    int wid = (blockIdx.x << 2) + (threadIdx.x >> 6);
    int lane = threadIdx.x & 63;
    int s = wid >> 10, j = wid & 1023;

    const float* Ws = W + (size_t)(s * (LL - 1) + (layer - 1)) * 4096 * HH;
    const float4* ri = (const float4*)(Ws + (size_t)(j) * HH);
    const float4* rg = (const float4*)(Ws + (size_t)(2048 + j) * HH);
    const float4* ro = (const float4*)(Ws + (size_t)(3072 + j) * HH);
    const float4* hv = (const float4*)(hin + s * HH);

    // Batch all loads first: 4 x h + 12 x w in flight per wave.
    float4 h0 = hv[lane],       h1 = hv[64 + lane];
    float4 h2 = hv[128 + lane], h3 = hv[192 + lane];
    float4 wi0 = ri[lane], wi1 = ri[64 + lane], wi2 = ri[128 + lane], wi3 = ri[192 + lane];
    float4 wg0 = rg[lane], wg1 = rg[64 + lane], wg2 = rg[128 + lane], wg3 = rg[192 + lane];
    float4 wo0 = ro[lane], wo1 = ro[64 + lane], wo2 = ro[128 + lane], wo3 = ro[192 + lane];

    float ai = dot4(wi0, h0) + dot4(wi1, h1) + dot4(wi2, h2) + dot4(wi3, h3);
    float ag = dot4(wg0, h0) + dot4(wg1, h1) + dot4(wg2, h2) + dot4(wg3, h3);
    float ao = dot4(wo0, h0) + dot4(wo1, h1) + dot4(wo2, h2) + dot4(wo3, h3);

    ai = wave_sum(ai); ag = wave_sum(ag); ao = wave_sum(ao);

    if (lane == 0) {
        const float* bi = b_ih + (size_t)(s * LL + layer) * 4096;
        const float* bh = b_hh + (size_t)(s * LL + layer) * 4096;
        float gi = ai + bi[j] + bh[j];
        float gg = ag + bi[2048 + j] + bh[2048 + j];
        float go = ao + bi[3072 + j] + bh[3072 + j];
        float c = sigf(gi) * tanhf(gg);
        hout[s * HH + j] = sigf(go) * tanhf(c);
    }
}

// ---------------------------------------------------------------------------
// 3) fuse: fused[j] = dot(fuse_w[j,:], hflat[0:5120]) + fuse_b[j]
//    (attention after this is a provable no-op: softmax over length-1 axis)
// ---------------------------------------------------------------------------
__global__ __launch_bounds__(256) void fuse_kernel(
    const float* __restrict__ fw,    // (H, S*H)
    const float* __restrict__ fb,    // (H)
    const float* __restrict__ hflat, // (S*H)
    float* __restrict__ fused)       // (H)
{
    int wid = (blockIdx.x << 2) + (threadIdx.x >> 6);
    int lane = threadIdx.x & 63;
    int j = wid;

    const float4* row = (const float4*)(fw + (size_t)j * (SS * HH));
    const float4* hv = (const float4*)hflat;
    float a = 0.0f;
#pragma unroll
    for (int k = 0; k < 20; ++k) {
        int idx = (k << 6) + lane;
        a += dot4(row[idx], hv[idx]);
    }
    a = wave_sum(a);
    if (lane == 0) fused[j] = a + fb[j];
}

// ---------------------------------------------------------------------------
// 4) fc: out[c] = dot(fc_w[c,:], fused) + fc_b[c]
// ---------------------------------------------------------------------------
__global__ __launch_bounds__(256) void fc_kernel(
    const float* __restrict__ fw,    // (C, H)
    const float* __restrict__ fb,    // (C)
    const float* __restrict__ fused, // (H)
    float* __restrict__ out)         // (C)
{
    int wid = (blockIdx.x << 2) + (threadIdx.x >> 6);
    int lane = threadIdx.x & 63;
    int c = wid;
    if (c >= CC) return;

    const float4* row = (const float4*)(fw + (size_t)c * HH);
    const float4* hv = (const float4*)fused;
    float4 w0 = row[lane],       w1 = row[64 + lane];
    float4 w2 = row[128 + lane], w3 = row[192 + lane];
    float4 h0 = hv[lane],        h1 = hv[64 + lane];
    float4 h2 = hv[128 + lane],  h3 = hv[192 + lane];
    float a = dot4(w0, h0) + dot4(w1, h1) + dot4(w2, h2) + dot4(w3, h3);
    a = wave_sum(a);
    if (lane == 0) out[c] = a + fb[c];
}

extern "C" void kernel_launch(void* const* d_in, const int* in_sizes, int n_in,
                              void* d_out, int out_size, void* d_ws, size_t ws_size,
                              hipStream_t stream) {
    const float* x      = (const float*)d_in[0];
    const float* W_ih0  = (const float*)d_in[1];
    const float* W_ihr  = (const float*)d_in[2];
    // d_in[3] = W_hh : multiplied by h0 == 0, never read
    const float* b_ih   = (const float*)d_in[4];
    const float* b_hh   = (const float*)d_in[5];
    const float* fuse_w = (const float*)d_in[6];
    const float* fuse_b = (const float*)d_in[7];
    // d_in[8..11] = att_w, att_b, score_w, score_b : softmax over len-1 axis => no-op
    const float* fc_w   = (const float*)d_in[12];
    const float* fc_b   = (const float*)d_in[13];
    float* out = (float*)d_out;

    float* ws    = (float*)d_ws;
    float* hA    = ws + WS_HA;
    float* hB    = ws + WS_HB;
    float* fused = ws + WS_FUSED;

    layer0_prep_kernel<<<1280, 256, 0, stream>>>(x, W_ih0, b_ih, b_hh, hA);
    layer_kernel<<<1280, 256, 0, stream>>>(W_ihr, b_ih, b_hh, 1, hA, hB);
    layer_kernel<<<1280, 256, 0, stream>>>(W_ihr, b_ih, b_hh, 2, hB, hA);
    layer_kernel<<<1280, 256, 0, stream>>>(W_ihr, b_ih, b_hh, 3, hA, hB);
    fuse_kernel<<<256, 256, 0, stream>>>(fuse_w, fuse_b, hB, fused);
    fc_kernel<<<125, 256, 0, stream>>>(fc_w, fc_b, fused, out);
}